// Round 16
// baseline (147.547 us; speedup 1.0000x reference)
//
#include <hip/hip_runtime.h>
#include <hip/hip_bf16.h>

#define DEVFN __device__ __forceinline__

typedef __bf16 bf16x8 __attribute__((ext_vector_type(8)));
typedef float f32x4 __attribute__((ext_vector_type(4)));
typedef float float4_t __attribute__((ext_vector_type(4)));
typedef unsigned short ushort8_t __attribute__((ext_vector_type(8)));
typedef unsigned short ushort4_t __attribute__((ext_vector_type(4)));
typedef unsigned int uint4_t __attribute__((ext_vector_type(4)));

constexpr int Bd = 8, Cd = 512, Nd = 4096, Dd = 64;

DEVFN unsigned short f2bf(float f) {
    union { float f; unsigned int u; } v; v.f = f;
    unsigned int r = (v.u + 0x7FFFu + ((v.u >> 16) & 1u)) >> 16;
    return (unsigned short)r;
}

DEVFN unsigned int pack2(float a, float b) {   // two f32 -> packed bf16x2 (RNE)
    __hip_bfloat162 h = __float22bfloat162_rn(make_float2(a, b));
    union { __hip_bfloat162 h; unsigned int u; } c; c.h = h;
    return c.u;
}

DEVFN bf16x8 ld_bf8(const unsigned short* p) {
    ushort8_t u = *(const ushort8_t*)p;
    return __builtin_bit_cast(bf16x8, u);
}

DEVFN f32x4 mfma16(bf16x8 a, bf16x8 b, f32x4 c) {
    return __builtin_amdgcn_mfma_f32_16x16x32_bf16(a, b, c, 0, 0, 0);
}

// ---------------- K0: convert weights to bf16 ----------------
__global__ __launch_bounds__(256) void k_cvtw(
    const float* __restrict__ Wq, const float* __restrict__ Wk,
    const float* __restrict__ Wv, const float* __restrict__ Wo,
    unsigned short* __restrict__ w4)
{
    int i = blockIdx.x * 256 + threadIdx.x;   // 0..32767
    w4[i]          = f2bf(Wq[i]);
    w4[32768 + i]  = f2bf(Wk[i]);
    w4[65536 + i]  = f2bf(Wv[i]);
    w4[98304 + i]  = f2bf(Wo[i]);
}

// ---------------- K1 v8: QKV with WIDE (512B/row) x reads ----------------
// Theory: all prior k_qkv variants read x in 64-128B segments at 16KB row
// stride -> DRAM page-activation-bound at ~1 TB/s (measured in every variant).
// v8: 128-n tile; each gload wave-instr covers 2 rows x 512B contiguous.
// x staged to LDS in natural (c,n) layout (ds_write_b64, no write transpose,
// hi-XOR column swizzle); A-frags = 8 offset-imm ds_read_u16 per lane.
// 512 thr = 8 waves, each 16 n x all 12 d-tiles. Grid 32x8 = 256 blocks.
__global__ __launch_bounds__(512, 2) void k_qkv(
    const float* __restrict__ x,
    const unsigned short* __restrict__ wq,
    const unsigned short* __restrict__ wk,
    const unsigned short* __restrict__ wv,
    const float* __restrict__ bq, const float* __restrict__ bk, const float* __restrict__ bv,
    unsigned short* __restrict__ q_nd, unsigned short* __restrict__ k_nd,
    unsigned short* __restrict__ v_dn)
{
    const int b   = blockIdx.y;
    const int n0  = blockIdx.x * 128;
    const int tid = threadIdx.x, wid = tid >> 6, l = tid & 63;
    const int lo  = l & 15, hi = l >> 4;
    const float* xb = x + (size_t)b * Cd * Nd;

    // x tiles, natural [c-local 64][n-local 128 + pad], column-swizzled:
    // element (c, n) stored at col n ^ (((c>>3)&3)*8).
    __shared__ __align__(16) unsigned short sm[2][64][136];   // 34.8 KB

    f32x4 acc[12] = {};

    const int lrow = l >> 5;          // 0..1: row parity within a wave-instr
    const int lcol = (l & 31) * 4;    // f32 column offset (32 lanes x 16B = 512B)
    float4_t xrA[4], xrB[4];

    auto gloadA = [&](int t) {
        const int c0 = t * 64;
        #pragma unroll
        for (int i = 0; i < 4; ++i)
            xrA[i] = *(const float4_t*)(xb + (size_t)(c0 + wid*8 + lrow + i*2) * Nd + n0 + lcol);
    };
    auto gloadB = [&](int t) {
        const int c0 = t * 64;
        #pragma unroll
        for (int i = 0; i < 4; ++i)
            xrB[i] = *(const float4_t*)(xb + (size_t)(c0 + wid*8 + lrow + i*2) * Nd + n0 + lcol);
    };
    const int wswz = (wid & 3) * 8;   // write-side col swizzle ((rl>>3)&3)*8, rl>>3 == wid
    auto dswriteA = [&](int buf) {
        #pragma unroll
        for (int i = 0; i < 4; ++i) {
            const int rl = wid*8 + lrow + i*2;
            ushort4_t u;
            #pragma unroll
            for (int j = 0; j < 4; ++j) u[j] = f2bf(xrA[i][j]);
            *(ushort4_t*)&sm[buf][rl][lcol ^ wswz] = u;
        }
    };
    auto dswriteB = [&](int buf) {
        #pragma unroll
        for (int i = 0; i < 4; ++i) {
            const int rl = wid*8 + lrow + i*2;
            ushort4_t u;
            #pragma unroll
            for (int j = 0; j < 4; ++j) u[j] = f2bf(xrB[i][j]);
            *(ushort4_t*)&sm[buf][rl][lcol ^ wswz] = u;
        }
    };
    auto compute = [&](int buf, int t) {
        #pragma unroll
        for (int kk = 0; kk < 2; ++kk) {
            // A-frag: n-row (wid*16+lo), c = kk*32 + hi*8 + j; read swizzle = hi*8
            const int rc = (wid*16 + lo) ^ (hi*8);
            ushort8_t ua;
            #pragma unroll
            for (int j = 0; j < 8; ++j)
                ua[j] = sm[buf][kk*32 + hi*8 + j][rc];
            bf16x8 af = __builtin_bit_cast(bf16x8, ua);
            #pragma unroll
            for (int jj = 0; jj < 12; ++jj) {
                const unsigned short* wm = (jj < 4) ? wq : (jj < 8) ? wk : wv;
                const int d0 = (jj & 3) * 16;
                bf16x8 bf = ld_bf8(wm + (d0 + lo) * Cd + t*64 + kk*32 + hi*8);
                acc[jj] = mfma16(af, bf, acc[jj]);
            }
        }
    };

    gloadA(0);
    dswriteA(0);
    gloadB(1);
    __syncthreads();
    for (int t = 0; t < 8; t += 2) {
        if (t + 2 < 8) gloadA(t + 2);            // prefetch 2 ahead
        __builtin_amdgcn_sched_barrier(0);       // pin loads (validated pattern)
        compute(0, t);
        dswriteB(1);
        __syncthreads();
        if (t + 3 < 8) gloadB(t + 3);
        __builtin_amdgcn_sched_barrier(0);
        compute(1, t + 1);
        if (t + 2 < 8) dswriteA(0);
        __syncthreads();
    }

    // ---- epilogue: q/k via per-wave transpose (wave-private [16][72] slices) ----
    unsigned short* epi = &sm[0][0][0];
    unsigned short* tl  = epi + wid * 16 * 72;
    #pragma unroll
    for (int m = 0; m < 2; ++m) {
        const float* bias = m ? bk : bq;
        #pragma unroll
        for (int jj = 0; jj < 4; ++jj) {
            const float bia = bias[jj*16 + lo];
            #pragma unroll
            for (int r = 0; r < 4; ++r)
                tl[(hi*4 + r) * 72 + jj*16 + lo] = f2bf(acc[m*4 + jj][r] + bia);
        }
        asm volatile("" ::: "memory");
        const int row = l >> 2, dg = l & 3;
        ushort8_t a0 = *(const ushort8_t*)&tl[row*72 + dg*16];
        ushort8_t a1 = *(const ushort8_t*)&tl[row*72 + dg*16 + 8];
        unsigned short* dst = (m ? k_nd : q_nd)
            + ((size_t)b * Nd + n0 + wid*16 + row) * 64 + dg*16;
        *(ushort8_t*)dst = a0; *(ushort8_t*)(dst + 8) = a1;
        asm volatile("" ::: "memory");
    }
    __syncthreads();                             // q/k region dead; reuse for v

    // ---- epilogue: v via block-wide [64 d][128 n] transpose (stride 136) ----
    unsigned short* vt2 = &sm[0][0][0];
    #pragma unroll
    for (int jj = 0; jj < 4; ++jj) {
        const float bia = bv[jj*16 + lo];
        #pragma unroll
        for (int r = 0; r < 4; ++r)
            vt2[(jj*16 + lo) * 136 + wid*16 + hi*4 + r] = f2bf(acc[8 + jj][r] + bia);
    }
    __syncthreads();
    {
        const int d = tid >> 3, nc = (tid & 7) * 16;
        ushort8_t a0 = *(const ushort8_t*)&vt2[d*136 + nc];
        ushort8_t a1 = *(const ushort8_t*)&vt2[d*136 + nc + 8];
        unsigned short* dst = v_dn + ((size_t)b * Dd + d) * Nd + n0 + nc;
        *(ushort8_t*)dst = a0; *(ushort8_t*)(dst + 8) = a1;
    }
}

// ---------------- K2 v5: flash attention, 128-key iterations (r15, best 61us) ----------------
__global__ __launch_bounds__(512, 4) void k_attn(
    const unsigned short* __restrict__ q_nd,
    const unsigned short* __restrict__ k_nd,
    const unsigned short* __restrict__ v_dn,
    unsigned short* __restrict__ o_nd)
{
    const int bid = blockIdx.x;
    const int b   = bid & 7;            // round-robin XCD dispatch -> batch-per-XCD L2 locality
    const int n0  = (bid >> 3) * 64;
    const int tid = threadIdx.x, wid = tid >> 6, l = tid & 63;
    const int lo  = l & 15, hi = l >> 4;
    const int lsw = lo & 7;
    const int qh  = wid >> 2;           // q-half (32 rows)
    const int kh  = (wid >> 1) & 1;     // key-half within tile (32 keys)
    const int tp  = wid & 1;            // tile parity within the 128-key pair
    const int wk0 = kh * 32;

    __shared__ __align__(16) unsigned short kv_lds[2][2][2][64 * 64];
    __shared__ float red_l[3][2][2][16];

    const unsigned short* qb = q_nd + (size_t)b * Nd * Dd;
    const unsigned short* kb = k_nd + (size_t)b * Nd * Dd;
    const unsigned short* vb = v_dn + (size_t)b * Dd * Nd;

    bf16x8 aq[2][2];
    #pragma unroll
    for (int qs = 0; qs < 2; ++qs)
        #pragma unroll
        for (int kc = 0; kc < 2; ++kc)
            aq[qs][kc] = ld_bf8(qb + (size_t)(n0 + qh*32 + qs*16 + lo) * 64 + kc*32 + hi*8);

    f32x4 acc[2][4] = {};
    float l_p[2] = {0.f, 0.f};

    const int sr = tid >> 3, ss = tid & 7;
    const int kwsl = (ss ^ (sr & 7)) * 8;
    const int vkh = ss >> 2, vsl = ss & 3, vms = vsl >> 1;
    const int vg0 = vkh * 4 + ((2 * vsl) & 3);
    const int vg1 = vkh * 4 + ((2 * vsl + 1) & 3);
    const int vsw = sr & 7;
    ushort8_t kr0, kr1, vr0, vr1;

    auto gload = [&](int it) {
        const size_t m1 = (size_t)it * 128;
        kr0 = *(const ushort8_t*)(kb + (m1 + sr) * 64 + ss * 8);
        kr1 = *(const ushort8_t*)(kb + (m1 + 64 + sr) * 64 + ss * 8);
        vr0 = *(const ushort8_t*)(vb + (size_t)sr * Nd + m1 + ss * 8);
        vr1 = *(const ushort8_t*)(vb + (size_t)sr * Nd + m1 + 64 + ss * 8);
    };
    auto dswrite = [&](int buf) {
        unsigned short* kt0 = &kv_lds[0][buf][0][0];
        unsigned short* kt1 = &kv_lds[0][buf][1][0];
        unsigned short* vt0 = &kv_lds[1][buf][0][0];
        unsigned short* vt1 = &kv_lds[1][buf][1][0];
        *(ushort8_t*)(kt0 + sr * 64 + kwsl) = kr0;
        *(ushort8_t*)(kt1 + sr * 64 + kwsl) = kr1;
        ushort4_t a0 = __builtin_shufflevector(vr0, vr0, 0, 1, 2, 3);
        ushort4_t a1 = __builtin_shufflevector(vr0, vr0, 4, 5, 6, 7);
        ushort4_t b0 = __builtin_shufflevector(vr1, vr1, 0, 1, 2, 3);
        ushort4_t b1 = __builtin_shufflevector(vr1, vr1, 4, 5, 6, 7);
        *(ushort4_t*)(vt0 + sr * 64 + (vg0 ^ vsw) * 8 + vms * 4) = a0;
        *(ushort4_t*)(vt0 + sr * 64 + (vg1 ^ vsw) * 8 + vms * 4) = a1;
        *(ushort4_t*)(vt1 + sr * 64 + (vg0 ^ vsw) * 8 + vms * 4) = b0;
        *(ushort4_t*)(vt1 + sr * 64 + (vg1 ^ vsw) * 8 + vms * 4) = b1;
    };

    auto compute = [&](int buf) {
        const unsigned short* kt = &kv_lds[0][buf][tp][0];
        const unsigned short* vt = &kv_lds[1][buf][tp][0];
        f32x4 s[2][2] = {};
        #pragma unroll
        for (int ms = 0; ms < 2; ++ms) {
            #pragma unroll
            for (int kc = 0; kc < 2; ++kc) {
                bf16x8 kf = ld_bf8(kt + (wk0 + ms*16 + lo) * 64 + (((kc*4 + hi) ^ lsw) * 8));
                #pragma unroll
                for (int qs = 0; qs < 2; ++qs)
                    s[qs][ms] = mfma16(kf, aq[qs][kc], s[qs][ms]);
            }
        }
        bf16x8 vf[4];
        #pragma unroll
        for (int ds = 0; ds < 4; ++ds)
            vf[ds] = ld_bf8(vt + (ds*16 + lo) * 64 + (((kh*4 + hi) ^ lsw) * 8));
        #pragma unroll
        for (int qs = 0; qs < 2; ++qs) {
            float p[2][4];
            #pragma unroll
            for (int ms = 0; ms < 2; ++ms)
                #pragma unroll
                for (int r = 0; r < 4; ++r)
                    p[ms][r] = __expf(s[qs][ms][r]);
            l_p[qs] += ((p[0][0] + p[0][1]) + (p[0][2] + p[0][3]))
                     + ((p[1][0] + p[1][1]) + (p[1][2] + p[1][3]));
            uint4_t w;
            w[0] = pack2(p[0][0], p[0][1]);
            w[1] = pack2(p[0][2], p[0][3]);
            w[2] = pack2(p[1][0], p[1][1]);
            w[3] = pack2(p[1][2], p[1][3]);
            bf16x8 apf = __builtin_bit_cast(bf16x8, w);
            #pragma unroll
            for (int ds = 0; ds < 4; ++ds)
                acc[qs][ds] = mfma16(apf, vf[ds], acc[qs][ds]);
        }
    };

    constexpr int NIT = Nd / 128;     // 32 iterations of 128 keys
    gload(0);
    dswrite(0);
    __syncthreads();
    for (int it = 0; it < NIT; ++it) {
        const int cur = it & 1;
        if (it + 1 < NIT) gload(it + 1);
        __builtin_amdgcn_sched_barrier(0);
        compute(cur);
        if (it + 1 < NIT) dswrite(cur ^ 1);
        __syncthreads();
    }

    float lh[2];
    #pragma unroll
    for (int qs = 0; qs < 2; ++qs) {
        float ps = l_p[qs];
        ps += __shfl_xor(ps, 16, 64);
        ps += __shfl_xor(ps, 32, 64);
        lh[qs] = ps;
    }
    float* red = (float*)&kv_lds[0][0][0][0];
    const int g = (kh * 2 + tp) - 1;
    if (g >= 0) {
        #pragma unroll
        for (int qs = 0; qs < 2; ++qs) {
            #pragma unroll
            for (int ds = 0; ds < 4; ++ds) {
                const int idx = ((g * 2 + qh) * 2 + qs) * 4 + ds;
                *(f32x4*)&red[idx * 256 + l * 4] = acc[qs][ds];
            }
            red_l[g][qh][qs][lo] = lh[qs];
        }
    }
    __syncthreads();
    if (g < 0) {
        #pragma unroll
        for (int qs = 0; qs < 2; ++qs) {
            #pragma unroll
            for (int gg = 0; gg < 3; ++gg) {
                #pragma unroll
                for (int ds = 0; ds < 4; ++ds) {
                    const int idx = ((gg * 2 + qh) * 2 + qs) * 4 + ds;
                    acc[qs][ds] += *(const f32x4*)&red[idx * 256 + l * 4];
                }
                lh[qs] += red_l[gg][qh][qs][lo];
            }
            #pragma unroll
            for (int r = 0; r < 4; ++r) {
                float lq = __shfl(lh[qs], hi * 4 + r, 16);
                float rl = 1.0f / lq;
                #pragma unroll
                for (int ds = 0; ds < 4; ++ds) {
                    float o = acc[qs][ds][r] * rl;
                    o_nd[((size_t)b * Nd + n0 + qh*32 + qs*16 + hi*4 + r) * 64 + ds*16 + lo] = f2bf(o);
                }
            }
        }
    }
}

// ---------------- K3: output projection + residual ----------------
__global__ __launch_bounds__(256) void k_oproj(
    const unsigned short* __restrict__ o_nd,
    const unsigned short* __restrict__ wo,
    const float* __restrict__ bo,
    const float* __restrict__ gamma,
    const float* __restrict__ x,
    float* __restrict__ out)
{
    const int b   = blockIdx.y;
    const int n0  = blockIdx.x * 64;
    const int tid = threadIdx.x, wid = tid >> 6, l = tid & 63;
    const int lo  = l & 15, hi = l >> 4;
    const int n0w = n0 + wid * 16;
    const float g = gamma[0];

    bf16x8 ao[2];
    #pragma unroll
    for (int kc = 0; kc < 2; ++kc)
        ao[kc] = ld_bf8(o_nd + ((size_t)b * Nd + n0w + lo) * 64 + kc*32 + hi*8);

    for (int ct = 0; ct < 32; ++ct) {
        f32x4 acc = {};
        #pragma unroll
        for (int kc = 0; kc < 2; ++kc) {
            bf16x8 bw = ld_bf8(wo + (ct*16 + lo) * 64 + kc*32 + hi*8);
            acc = mfma16(ao[kc], bw, acc);
        }
        const int c = ct*16 + lo;
        const float bc = bo[c];
        const size_t base = ((size_t)b * Cd + c) * Nd + n0w + hi*4;
        float4_t xv = *(const float4_t*)(x + base);
        float4_t ov;
        #pragma unroll
        for (int r = 0; r < 4; ++r) ov[r] = g * (acc[r] + bc) + xv[r];
        *(float4_t*)(out + base) = ov;
    }
}

extern "C" void kernel_launch(void* const* d_in, const int* in_sizes, int n_in,
                              void* d_out, int out_size, void* d_ws, size_t ws_size,
                              hipStream_t stream) {
    (void)in_sizes; (void)n_in; (void)out_size; (void)ws_size;
    const float* x  = (const float*)d_in[0];
    const float* Wq = (const float*)d_in[1];
    const float* bq = (const float*)d_in[2];
    const float* Wk = (const float*)d_in[3];
    const float* bk = (const float*)d_in[4];
    const float* Wv = (const float*)d_in[5];
    const float* bv = (const float*)d_in[6];
    const float* Wo = (const float*)d_in[7];
    const float* bo = (const float*)d_in[8];
    const float* gm = (const float*)d_in[9];
    float* out = (float*)d_out;

    unsigned short* w4   = (unsigned short*)d_ws;          // 4 x 32768 bf16 weights
    unsigned short* q_nd = w4 + 131072;
    unsigned short* k_nd = q_nd + (size_t)Bd * Nd * Dd;
    unsigned short* v_dn = k_nd + (size_t)Bd * Nd * Dd;
    unsigned short* o_nd = v_dn + (size_t)Bd * Nd * Dd;

    k_cvtw<<<128, 256, 0, stream>>>(Wq, Wk, Wv, Wo, w4);
    dim3 gq(Nd / 128, Bd);
    k_qkv<<<gq, 512, 0, stream>>>(x, w4, w4 + 32768, w4 + 65536, bq, bk, bv, q_nd, k_nd, v_dn);
    k_attn<<<512, 512, 0, stream>>>(q_nd, k_nd, v_dn, o_nd);
    dim3 g1(Nd / 64, Bd);
    k_oproj<<<g1, 256, 0, stream>>>(o_nd, w4 + 98304, bo, gm, x, out);
}

// Round 17
// 141.866 us; speedup vs baseline: 1.0400x; 1.0400x over previous
//
#include <hip/hip_runtime.h>
#include <hip/hip_bf16.h>

#define DEVFN __device__ __forceinline__

typedef __bf16 bf16x8 __attribute__((ext_vector_type(8)));
typedef float f32x4 __attribute__((ext_vector_type(4)));
typedef float float4_t __attribute__((ext_vector_type(4)));
typedef unsigned short ushort8_t __attribute__((ext_vector_type(8)));
typedef unsigned short ushort4_t __attribute__((ext_vector_type(4)));
typedef unsigned int uint4_t __attribute__((ext_vector_type(4)));

constexpr int Bd = 8, Cd = 512, Nd = 4096, Dd = 64;

DEVFN unsigned short f2bf(float f) {
    union { float f; unsigned int u; } v; v.f = f;
    unsigned int r = (v.u + 0x7FFFu + ((v.u >> 16) & 1u)) >> 16;
    return (unsigned short)r;
}

DEVFN unsigned int pack2(float a, float b) {   // two f32 -> packed bf16x2 (RNE)
    __hip_bfloat162 h = __float22bfloat162_rn(make_float2(a, b));
    union { __hip_bfloat162 h; unsigned int u; } c; c.h = h;
    return c.u;
}

DEVFN bf16x8 ld_bf8(const unsigned short* p) {
    ushort8_t u = *(const ushort8_t*)p;
    return __builtin_bit_cast(bf16x8, u);
}

DEVFN f32x4 mfma16(bf16x8 a, bf16x8 b, f32x4 c) {
    return __builtin_amdgcn_mfma_f32_16x16x32_bf16(a, b, c, 0, 0, 0);
}

// ---------------- K0: convert weights to bf16 ----------------
__global__ __launch_bounds__(256) void k_cvtw(
    const float* __restrict__ Wq, const float* __restrict__ Wk,
    const float* __restrict__ Wv, const float* __restrict__ Wo,
    unsigned short* __restrict__ w4)
{
    int i = blockIdx.x * 256 + threadIdx.x;   // 0..32767
    w4[i]          = f2bf(Wq[i]);
    w4[32768 + i]  = f2bf(Wk[i]);
    w4[65536 + i]  = f2bf(Wv[i]);
    w4[98304 + i]  = f2bf(Wo[i]);
}

// ---------------- K1 v9: QKV "load-all-then-compute", zero mid-loop barriers ----------------
// k_oproj evidence: the same strided x pattern sustains ~8 TB/s effective when
// loads are deep and un-drained. v9: phase 1 loads the WHOLE 512c x 64n chunk
// (32 independent float4/thread), cvt->bf16 into LDS natural layout with XOR-16
// column swizzle (conflict-free fragment reads, no pad -> exactly 64 KB).
// Phase 2 after ONE barrier: pure barrier-free compute (waves independent),
// A-frags = 8x ds_read_u16, B-frags = L2-hot weights. 2 blocks/CU overlap
// (one loads while the other computes). Epilogues = r6/r9 validated.
__global__ __launch_bounds__(256, 2) void k_qkv(
    const float* __restrict__ x,
    const unsigned short* __restrict__ wq,
    const unsigned short* __restrict__ wk,
    const unsigned short* __restrict__ wv,
    const float* __restrict__ bq, const float* __restrict__ bk, const float* __restrict__ bv,
    unsigned short* __restrict__ q_nd, unsigned short* __restrict__ k_nd,
    unsigned short* __restrict__ v_dn)
{
    const int b   = blockIdx.y;
    const int n0  = blockIdx.x * 64;
    const int tid = threadIdx.x, wid = tid >> 6, l = tid & 63;
    const int lo  = l & 15, hi = l >> 4;
    const float* xb = x + (size_t)b * Cd * Nd + n0;

    // x chunk, natural [c 512][n 64] bf16; element (c,n) at col n ^ (((c>>3)&3)<<4)
    __shared__ __align__(16) unsigned short sm[512 * 64];    // exactly 64 KB

    // ---- phase 1: load entire chunk with deep MLP, two 16-deep bursts ----
    const int lr = tid >> 4;            // 0..15
    const int nc = (tid & 15) * 4;      // f32 col offset
    #pragma unroll
    for (int half = 0; half < 2; ++half) {
        float4_t xr[16];
        #pragma unroll
        for (int r = 0; r < 16; ++r) {
            const int c = half * 256 + r * 16 + lr;
            xr[r] = *(const float4_t*)(xb + (size_t)c * Nd + nc);
        }
        __builtin_amdgcn_sched_barrier(0);       // keep the 16 loads issued as a burst
        #pragma unroll
        for (int r = 0; r < 16; ++r) {
            const int c = half * 256 + r * 16 + lr;
            const int s = ((c >> 3) & 3) << 4;
            ushort4_t u;
            #pragma unroll
            for (int j = 0; j < 4; ++j) u[j] = f2bf(xr[r][j]);
            *(ushort4_t*)&sm[c * 64 + (nc ^ s)] = u;
        }
    }
    __syncthreads();                             // the ONLY pre-epilogue barrier

    // ---- phase 2: barrier-free compute; wave = 16 n-rows x all 12 d-tiles ----
    f32x4 acc[12] = {};
    for (int t = 0; t < 8; ++t) {
        #pragma unroll
        for (int kk = 0; kk < 2; ++kk) {
            const int cbase = t * 64 + kk * 32 + hi * 8;
            const int s   = ((cbase >> 3) & 3) << 4;   // constant over j (cbase % 8 == 0)
            const int col = (wid * 16 + lo) ^ s;
            ushort8_t ua;
            #pragma unroll
            for (int j = 0; j < 8; ++j)
                ua[j] = sm[(cbase + j) * 64 + col];
            bf16x8 af = __builtin_bit_cast(bf16x8, ua);
            #pragma unroll
            for (int jj = 0; jj < 12; ++jj) {
                const unsigned short* wm = (jj < 4) ? wq : (jj < 8) ? wk : wv;
                const int d0 = (jj & 3) * 16;
                bf16x8 bf = ld_bf8(wm + (d0 + lo) * Cd + t * 64 + kk * 32 + hi * 8);
                acc[jj] = mfma16(af, bf, acc[jj]);
            }
        }
    }
    __syncthreads();                             // x region dead; overlay epilogues

    // ---- epilogue: q/k via per-wave transpose (validated r9 pattern) ----
    unsigned short* tl = sm + wid * (16 * 72);   // wave-private [16][72]
    #pragma unroll
    for (int m = 0; m < 2; ++m) {
        const float* bias = m ? bk : bq;
        #pragma unroll
        for (int jj = 0; jj < 4; ++jj) {
            const float bia = bias[jj * 16 + lo];
            #pragma unroll
            for (int r = 0; r < 4; ++r)
                tl[(hi * 4 + r) * 72 + jj * 16 + lo] = f2bf(acc[m * 4 + jj][r] + bia);
        }
        asm volatile("" ::: "memory");           // in-wave: reads after writes
        const int row = l >> 2, dg = l & 3;
        ushort8_t a0 = *(const ushort8_t*)&tl[row * 72 + dg * 16];
        ushort8_t a1 = *(const ushort8_t*)&tl[row * 72 + dg * 16 + 8];
        unsigned short* dst = (m ? k_nd : q_nd)
            + ((size_t)b * Nd + n0 + wid * 16 + row) * 64 + dg * 16;
        *(ushort8_t*)dst = a0; *(ushort8_t*)(dst + 8) = a1;
        asm volatile("" ::: "memory");           // m=0 reads before m=1 overwrites
    }
    __syncthreads();

    // ---- epilogue: v via block-wide [64 d][72] transpose (validated r6 pattern) ----
    unsigned short* vt = sm;
    #pragma unroll
    for (int jj = 0; jj < 4; ++jj) {
        const float bia = bv[jj * 16 + lo];
        #pragma unroll
        for (int r = 0; r < 4; ++r)
            vt[(jj * 16 + lo) * 72 + wid * 16 + hi * 4 + r] = f2bf(acc[8 + jj][r] + bia);
    }
    __syncthreads();
    {
        const int d = tid >> 2, ng = tid & 3;
        ushort8_t a0 = *(const ushort8_t*)&vt[d * 72 + ng * 16];
        ushort8_t a1 = *(const ushort8_t*)&vt[d * 72 + ng * 16 + 8];
        unsigned short* dst = v_dn + ((size_t)b * Dd + d) * Nd + n0 + ng * 16;
        *(ushort8_t*)dst = a0; *(ushort8_t*)(dst + 8) = a1;
    }
}

// ---------------- K2 v5: flash attention, 128-key iterations (r15, best 61us) ----------------
__global__ __launch_bounds__(512, 4) void k_attn(
    const unsigned short* __restrict__ q_nd,
    const unsigned short* __restrict__ k_nd,
    const unsigned short* __restrict__ v_dn,
    unsigned short* __restrict__ o_nd)
{
    const int bid = blockIdx.x;
    const int b   = bid & 7;            // round-robin XCD dispatch -> batch-per-XCD L2 locality
    const int n0  = (bid >> 3) * 64;
    const int tid = threadIdx.x, wid = tid >> 6, l = tid & 63;
    const int lo  = l & 15, hi = l >> 4;
    const int lsw = lo & 7;
    const int qh  = wid >> 2;           // q-half (32 rows)
    const int kh  = (wid >> 1) & 1;     // key-half within tile (32 keys)
    const int tp  = wid & 1;            // tile parity within the 128-key pair
    const int wk0 = kh * 32;

    __shared__ __align__(16) unsigned short kv_lds[2][2][2][64 * 64];
    __shared__ float red_l[3][2][2][16];

    const unsigned short* qb = q_nd + (size_t)b * Nd * Dd;
    const unsigned short* kb = k_nd + (size_t)b * Nd * Dd;
    const unsigned short* vb = v_dn + (size_t)b * Dd * Nd;

    bf16x8 aq[2][2];
    #pragma unroll
    for (int qs = 0; qs < 2; ++qs)
        #pragma unroll
        for (int kc = 0; kc < 2; ++kc)
            aq[qs][kc] = ld_bf8(qb + (size_t)(n0 + qh*32 + qs*16 + lo) * 64 + kc*32 + hi*8);

    f32x4 acc[2][4] = {};
    float l_p[2] = {0.f, 0.f};

    const int sr = tid >> 3, ss = tid & 7;
    const int kwsl = (ss ^ (sr & 7)) * 8;
    const int vkh = ss >> 2, vsl = ss & 3, vms = vsl >> 1;
    const int vg0 = vkh * 4 + ((2 * vsl) & 3);
    const int vg1 = vkh * 4 + ((2 * vsl + 1) & 3);
    const int vsw = sr & 7;
    ushort8_t kr0, kr1, vr0, vr1;

    auto gload = [&](int it) {
        const size_t m1 = (size_t)it * 128;
        kr0 = *(const ushort8_t*)(kb + (m1 + sr) * 64 + ss * 8);
        kr1 = *(const ushort8_t*)(kb + (m1 + 64 + sr) * 64 + ss * 8);
        vr0 = *(const ushort8_t*)(vb + (size_t)sr * Nd + m1 + ss * 8);
        vr1 = *(const ushort8_t*)(vb + (size_t)sr * Nd + m1 + 64 + ss * 8);
    };
    auto dswrite = [&](int buf) {
        unsigned short* kt0 = &kv_lds[0][buf][0][0];
        unsigned short* kt1 = &kv_lds[0][buf][1][0];
        unsigned short* vt0 = &kv_lds[1][buf][0][0];
        unsigned short* vt1 = &kv_lds[1][buf][1][0];
        *(ushort8_t*)(kt0 + sr * 64 + kwsl) = kr0;
        *(ushort8_t*)(kt1 + sr * 64 + kwsl) = kr1;
        ushort4_t a0 = __builtin_shufflevector(vr0, vr0, 0, 1, 2, 3);
        ushort4_t a1 = __builtin_shufflevector(vr0, vr0, 4, 5, 6, 7);
        ushort4_t b0 = __builtin_shufflevector(vr1, vr1, 0, 1, 2, 3);
        ushort4_t b1 = __builtin_shufflevector(vr1, vr1, 4, 5, 6, 7);
        *(ushort4_t*)(vt0 + sr * 64 + (vg0 ^ vsw) * 8 + vms * 4) = a0;
        *(ushort4_t*)(vt0 + sr * 64 + (vg1 ^ vsw) * 8 + vms * 4) = a1;
        *(ushort4_t*)(vt1 + sr * 64 + (vg0 ^ vsw) * 8 + vms * 4) = b0;
        *(ushort4_t*)(vt1 + sr * 64 + (vg1 ^ vsw) * 8 + vms * 4) = b1;
    };

    auto compute = [&](int buf) {
        const unsigned short* kt = &kv_lds[0][buf][tp][0];
        const unsigned short* vt = &kv_lds[1][buf][tp][0];
        f32x4 s[2][2] = {};
        #pragma unroll
        for (int ms = 0; ms < 2; ++ms) {
            #pragma unroll
            for (int kc = 0; kc < 2; ++kc) {
                bf16x8 kf = ld_bf8(kt + (wk0 + ms*16 + lo) * 64 + (((kc*4 + hi) ^ lsw) * 8));
                #pragma unroll
                for (int qs = 0; qs < 2; ++qs)
                    s[qs][ms] = mfma16(kf, aq[qs][kc], s[qs][ms]);
            }
        }
        bf16x8 vf[4];
        #pragma unroll
        for (int ds = 0; ds < 4; ++ds)
            vf[ds] = ld_bf8(vt + (ds*16 + lo) * 64 + (((kh*4 + hi) ^ lsw) * 8));
        #pragma unroll
        for (int qs = 0; qs < 2; ++qs) {
            float p[2][4];
            #pragma unroll
            for (int ms = 0; ms < 2; ++ms)
                #pragma unroll
                for (int r = 0; r < 4; ++r)
                    p[ms][r] = __expf(s[qs][ms][r]);
            l_p[qs] += ((p[0][0] + p[0][1]) + (p[0][2] + p[0][3]))
                     + ((p[1][0] + p[1][1]) + (p[1][2] + p[1][3]));
            uint4_t w;
            w[0] = pack2(p[0][0], p[0][1]);
            w[1] = pack2(p[0][2], p[0][3]);
            w[2] = pack2(p[1][0], p[1][1]);
            w[3] = pack2(p[1][2], p[1][3]);
            bf16x8 apf = __builtin_bit_cast(bf16x8, w);
            #pragma unroll
            for (int ds = 0; ds < 4; ++ds)
                acc[qs][ds] = mfma16(apf, vf[ds], acc[qs][ds]);
        }
    };

    constexpr int NIT = Nd / 128;     // 32 iterations of 128 keys
    gload(0);
    dswrite(0);
    __syncthreads();
    for (int it = 0; it < NIT; ++it) {
        const int cur = it & 1;
        if (it + 1 < NIT) gload(it + 1);
        __builtin_amdgcn_sched_barrier(0);
        compute(cur);
        if (it + 1 < NIT) dswrite(cur ^ 1);
        __syncthreads();
    }

    float lh[2];
    #pragma unroll
    for (int qs = 0; qs < 2; ++qs) {
        float ps = l_p[qs];
        ps += __shfl_xor(ps, 16, 64);
        ps += __shfl_xor(ps, 32, 64);
        lh[qs] = ps;
    }
    float* red = (float*)&kv_lds[0][0][0][0];
    const int g = (kh * 2 + tp) - 1;
    if (g >= 0) {
        #pragma unroll
        for (int qs = 0; qs < 2; ++qs) {
            #pragma unroll
            for (int ds = 0; ds < 4; ++ds) {
                const int idx = ((g * 2 + qh) * 2 + qs) * 4 + ds;
                *(f32x4*)&red[idx * 256 + l * 4] = acc[qs][ds];
            }
            red_l[g][qh][qs][lo] = lh[qs];
        }
    }
    __syncthreads();
    if (g < 0) {
        #pragma unroll
        for (int qs = 0; qs < 2; ++qs) {
            #pragma unroll
            for (int gg = 0; gg < 3; ++gg) {
                #pragma unroll
                for (int ds = 0; ds < 4; ++ds) {
                    const int idx = ((gg * 2 + qh) * 2 + qs) * 4 + ds;
                    acc[qs][ds] += *(const f32x4*)&red[idx * 256 + l * 4];
                }
                lh[qs] += red_l[gg][qh][qs][lo];
            }
            #pragma unroll
            for (int r = 0; r < 4; ++r) {
                float lq = __shfl(lh[qs], hi * 4 + r, 16);
                float rl = 1.0f / lq;
                #pragma unroll
                for (int ds = 0; ds < 4; ++ds) {
                    float o = acc[qs][ds][r] * rl;
                    o_nd[((size_t)b * Nd + n0 + qh*32 + qs*16 + hi*4 + r) * 64 + ds*16 + lo] = f2bf(o);
                }
            }
        }
    }
}

// ---------------- K3: output projection + residual ----------------
__global__ __launch_bounds__(256) void k_oproj(
    const unsigned short* __restrict__ o_nd,
    const unsigned short* __restrict__ wo,
    const float* __restrict__ bo,
    const float* __restrict__ gamma,
    const float* __restrict__ x,
    float* __restrict__ out)
{
    const int b   = blockIdx.y;
    const int n0  = blockIdx.x * 64;
    const int tid = threadIdx.x, wid = tid >> 6, l = tid & 63;
    const int lo  = l & 15, hi = l >> 4;
    const int n0w = n0 + wid * 16;
    const float g = gamma[0];

    bf16x8 ao[2];
    #pragma unroll
    for (int kc = 0; kc < 2; ++kc)
        ao[kc] = ld_bf8(o_nd + ((size_t)b * Nd + n0w + lo) * 64 + kc*32 + hi*8);

    for (int ct = 0; ct < 32; ++ct) {
        f32x4 acc = {};
        #pragma unroll
        for (int kc = 0; kc < 2; ++kc) {
            bf16x8 bw = ld_bf8(wo + (ct*16 + lo) * 64 + kc*32 + hi*8);
            acc = mfma16(ao[kc], bw, acc);
        }
        const int c = ct*16 + lo;
        const float bc = bo[c];
        const size_t base = ((size_t)b * Cd + c) * Nd + n0w + hi*4;
        float4_t xv = *(const float4_t*)(x + base);
        float4_t ov;
        #pragma unroll
        for (int r = 0; r < 4; ++r) ov[r] = g * (acc[r] + bc) + xv[r];
        *(float4_t*)(out + base) = ov;
    }
}

extern "C" void kernel_launch(void* const* d_in, const int* in_sizes, int n_in,
                              void* d_out, int out_size, void* d_ws, size_t ws_size,
                              hipStream_t stream) {
    (void)in_sizes; (void)n_in; (void)out_size; (void)ws_size;
    const float* x  = (const float*)d_in[0];
    const float* Wq = (const float*)d_in[1];
    const float* bq = (const float*)d_in[2];
    const float* Wk = (const float*)d_in[3];
    const float* bk = (const float*)d_in[4];
    const float* Wv = (const float*)d_in[5];
    const float* bv = (const float*)d_in[6];
    const float* Wo = (const float*)d_in[7];
    const float* bo = (const float*)d_in[8];
    const float* gm = (const float*)d_in[9];
    float* out = (float*)d_out;

    unsigned short* w4   = (unsigned short*)d_ws;          // 4 x 32768 bf16 weights
    unsigned short* q_nd = w4 + 131072;
    unsigned short* k_nd = q_nd + (size_t)Bd * Nd * Dd;
    unsigned short* v_dn = k_nd + (size_t)Bd * Nd * Dd;
    unsigned short* o_nd = v_dn + (size_t)Bd * Nd * Dd;

    k_cvtw<<<128, 256, 0, stream>>>(Wq, Wk, Wv, Wo, w4);
    dim3 gq(Nd / 64, Bd);
    k_qkv<<<gq, 256, 0, stream>>>(x, w4, w4 + 32768, w4 + 65536, bq, bk, bv, q_nd, k_nd, v_dn);
    k_attn<<<512, 512, 0, stream>>>(q_nd, k_nd, v_dn, o_nd);
    dim3 g1(Nd / 64, Bd);
    k_oproj<<<g1, 256, 0, stream>>>(o_nd, w4 + 98304, bo, gm, x, out);
}